// Round 2
// baseline (988.024 us; speedup 1.0000x reference)
//
#include <hip/hip_runtime.h>
#include <hip/hip_bf16.h>
#include <math.h>

#define NEG_SLOPE 0.2f

// ---------------------------------------------------------------------------
// K1: h = x @ W + b_W  (N x 128, f32), plus per-node attention scalars
//     ai[n,hh] = dot(att[hh, 0:64],  h[n, hh*64:(hh+1)*64])   (x_i term)
//     aj[n,hh] = dot(att[hh,64:128], h[n, hh*64:(hh+1)*64])   (x_j term)
// block = 128 threads (2 waves); wave w == head w for the reduction.
// ---------------------------------------------------------------------------
__global__ __launch_bounds__(128) void k1_gemm(
    const float* __restrict__ x, const float* __restrict__ W,
    const float* __restrict__ bW, const float* __restrict__ att,
    float* __restrict__ h, float* __restrict__ ai, float* __restrict__ aj, int Nn) {
  __shared__ float Ws[64 * 128];
  __shared__ float xs[64];
  __shared__ float bs[128];
  __shared__ float atts[256];
  int t = threadIdx.x;  // 0..127
  for (int i = t; i < 64 * 128; i += 128) Ws[i] = W[i];
  bs[t] = bW[t];
  atts[t] = att[t];
  atts[128 + t] = att[128 + t];
  __syncthreads();
  int wave = t >> 6;   // head index
  int lane = t & 63;   // d index within head
  for (int row = blockIdx.x; row < Nn; row += gridDim.x) {
    if (t < 64) xs[t] = x[(size_t)row * 64 + t];
    __syncthreads();
    float acc = bs[t];
#pragma unroll
    for (int k = 0; k < 64; ++k) acc += xs[k] * Ws[k * 128 + t];
    h[(size_t)row * 128 + t] = acc;
    // reduce per-head dot products across the wave (64 lanes)
    float ti = atts[wave * 128 + lane] * acc;        // x_i coefficient
    float tj = atts[wave * 128 + 64 + lane] * acc;   // x_j coefficient
#pragma unroll
    for (int off = 32; off > 0; off >>= 1) {
      ti += __shfl_down(ti, off, 64);
      tj += __shfl_down(tj, off, 64);
    }
    if (lane == 0) { ai[row * 2 + wave] = ti; aj[row * 2 + wave] = tj; }
    __syncthreads();
  }
}

// ---------------------------------------------------------------------------
// K2: per-edge attention logits + leaky relu + exp (no max subtraction:
// logits are O(10), exp is safe in f32 and the softmax ratio is identical),
// atomicAdd into per-(src,head) sums. Edge-emb term via 30-entry LDS table
// tbl[f][c][hh] = dot(att_j[hh], bond_emb[f][c][hh*64:..]).
// ---------------------------------------------------------------------------
__global__ __launch_bounds__(256) void k2_logits(
    const int* __restrict__ ei, const int* __restrict__ eattr,
    const float* __restrict__ att, const float* __restrict__ bemb,
    const float* __restrict__ ai, const float* __restrict__ aj,
    float* __restrict__ ea, float* __restrict__ sbuf, int Ee) {
  __shared__ float tbl[30];  // [f][c][hh] = f*10 + c*2 + hh
  int t = threadIdx.x;
  if (t < 30) {
    int f = t / 10, rem = t % 10, c = rem >> 1, hh = rem & 1;
    float sacc = 0.f;
    for (int d = 0; d < 64; ++d)
      sacc += att[hh * 128 + 64 + d] * bemb[(f * 5 + c) * 128 + hh * 64 + d];
    tbl[t] = sacc;
  }
  __syncthreads();
  int stride = gridDim.x * blockDim.x;
  for (int e = blockIdx.x * blockDim.x + t; e < Ee; e += stride) {
    int r = ei[e], c = ei[Ee + e];
    int a0 = eattr[e * 3], a1 = eattr[e * 3 + 1], a2 = eattr[e * 3 + 2];
#pragma unroll
    for (int hh = 0; hh < 2; ++hh) {
      float lg = ai[c * 2 + hh] + aj[r * 2 + hh] +
                 tbl[a0 * 2 + hh] + tbl[10 + a1 * 2 + hh] + tbl[20 + a2 * 2 + hh];
      lg = lg >= 0.f ? lg : NEG_SLOPE * lg;
      float v = __expf(lg);
      ea[(size_t)e * 2 + hh] = v;
      atomicAdd(&sbuf[r * 2 + hh], v);
    }
  }
}

// ---------------------------------------------------------------------------
// K3: weighted message scatter. One wave per edge; lane = d (0..63), both
// heads per lane. msg = alpha * (h[src] + e_emb), atomicAdd into aggr[dst].
// bond_emb staged to LDS (7.5 KB).
// ---------------------------------------------------------------------------
__global__ __launch_bounds__(256) void k3_scatter(
    const int* __restrict__ ei, const int* __restrict__ eattr,
    const float* __restrict__ bemb, const float* __restrict__ h,
    const float* __restrict__ ea, const float* __restrict__ sbuf,
    float* __restrict__ aggr, int Ee) {
  __shared__ float bembs[3 * 5 * 128];
  for (int i = threadIdx.x; i < 3 * 5 * 128; i += blockDim.x)
    bembs[i] = bemb[i];
  __syncthreads();
  int gwave = (blockIdx.x * blockDim.x + threadIdx.x) >> 6;
  int lane = threadIdx.x & 63;
  int nwaves = (gridDim.x * blockDim.x) >> 6;
  for (int e = gwave; e < Ee; e += nwaves) {
    int r = ei[e], c = ei[Ee + e];
    int a0 = eattr[e * 3] * 128;
    int a1 = eattr[e * 3 + 1] * 128 + 640;
    int a2 = eattr[e * 3 + 2] * 128 + 1280;
    float s0 = sbuf[r * 2] + 1e-16f, s1 = sbuf[r * 2 + 1] + 1e-16f;
    float al0 = ea[(size_t)e * 2] / s0;
    float al1 = ea[(size_t)e * 2 + 1] / s1;
    float v0 = h[(size_t)r * 128 + lane] + bembs[a0 + lane] + bembs[a1 + lane] + bembs[a2 + lane];
    float v1 = h[(size_t)r * 128 + 64 + lane] + bembs[a0 + 64 + lane] + bembs[a1 + 64 + lane] + bembs[a2 + 64 + lane];
    atomicAdd(&aggr[(size_t)c * 128 + lane], al0 * v0);
    atomicAdd(&aggr[(size_t)c * 128 + 64 + lane], al1 * v1);
  }
}

// ---------------------------------------------------------------------------
// K4: out[n,d] = 0.5*(aggr[n,0,d] + aggr[n,1,d]) + bias[d]
// ---------------------------------------------------------------------------
__global__ __launch_bounds__(256) void k4_out(
    const float* __restrict__ aggr, const float* __restrict__ bias,
    float* __restrict__ out, int Nn) {
  int total = Nn * 64;
  int stride = gridDim.x * blockDim.x;
  for (int i = blockIdx.x * blockDim.x + threadIdx.x; i < total; i += stride) {
    int n = i >> 6, d = i & 63;
    float v = 0.5f * (aggr[(size_t)n * 128 + d] + aggr[(size_t)n * 128 + 64 + d]) +
              bias[d];
    out[i] = v;
  }
}

extern "C" void kernel_launch(void* const* d_in, const int* in_sizes, int n_in,
                              void* d_out, int out_size, void* d_ws, size_t ws_size,
                              hipStream_t stream) {
  const float* x    = (const float*)d_in[0];
  const int*   ei   = (const int*)d_in[1];
  const int*   eatt = (const int*)d_in[2];
  const float* W    = (const float*)d_in[3];
  const float* bW   = (const float*)d_in[4];
  const float* att  = (const float*)d_in[5];
  const float* bias = (const float*)d_in[6];
  const float* bemb = (const float*)d_in[7];
  int Nn = in_sizes[0] / 64;
  int Ee = in_sizes[1] / 2;

  char* ws = (char*)d_ws;
  float* h = (float*)ws;          ws += (size_t)Nn * 128 * 4;
  float* ai = (float*)ws;         ws += (size_t)Nn * 2 * 4;
  float* aj = (float*)ws;         ws += (size_t)Nn * 2 * 4;
  float* sbuf = (float*)ws;       ws += (size_t)Nn * 2 * 4;
  float* eabuf = (float*)ws;      ws += (size_t)Ee * 2 * 4;
  float* aggr = (float*)ws;       ws += (size_t)Nn * 128 * 4;

  hipMemsetAsync(sbuf, 0, (size_t)Nn * 2 * 4, stream);
  hipMemsetAsync(aggr, 0, (size_t)Nn * 128 * 4, stream);

  k1_gemm<<<1024, 128, 0, stream>>>(x, W, bW, att, h, ai, aj, Nn);
  k2_logits<<<2048, 256, 0, stream>>>(ei, eatt, att, bemb, ai, aj, eabuf, sbuf, Ee);
  k3_scatter<<<4096, 256, 0, stream>>>(ei, eatt, bemb, h, eabuf, sbuf, aggr, Ee);
  k4_out<<<2048, 256, 0, stream>>>(aggr, bias, (float*)d_out, Nn);
}

// Round 3
// 664.231 us; speedup vs baseline: 1.4875x; 1.4875x over previous
//
#include <hip/hip_runtime.h>
#include <hip/hip_bf16.h>
#include <math.h>

#define NEG_SLOPE 0.2f

// ---------------------------------------------------------------------------
// K1: h = x @ W + b_W  (N x 128, f32), plus per-node attention scalars
//     ai[n,hh] = dot(att[hh, 0:64],  h[n, hh*64:..])   (x_i term)
//     aj[n,hh] = dot(att[hh,64:128], h[n, hh*64:..])   (x_j term)
// ---------------------------------------------------------------------------
__global__ __launch_bounds__(128) void k1_gemm(
    const float* __restrict__ x, const float* __restrict__ W,
    const float* __restrict__ bW, const float* __restrict__ att,
    float* __restrict__ h, float* __restrict__ ai, float* __restrict__ aj, int Nn) {
  __shared__ float Ws[64 * 128];
  __shared__ float xs[64];
  __shared__ float bs[128];
  __shared__ float atts[256];
  int t = threadIdx.x;  // 0..127
  for (int i = t; i < 64 * 128; i += 128) Ws[i] = W[i];
  bs[t] = bW[t];
  atts[t] = att[t];
  atts[128 + t] = att[128 + t];
  __syncthreads();
  int wave = t >> 6;   // head index
  int lane = t & 63;   // d index within head
  for (int row = blockIdx.x; row < Nn; row += gridDim.x) {
    if (t < 64) xs[t] = x[(size_t)row * 64 + t];
    __syncthreads();
    float acc = bs[t];
#pragma unroll
    for (int k = 0; k < 64; ++k) acc += xs[k] * Ws[k * 128 + t];
    h[(size_t)row * 128 + t] = acc;
    float ti = atts[wave * 128 + lane] * acc;
    float tj = atts[wave * 128 + 64 + lane] * acc;
#pragma unroll
    for (int off = 32; off > 0; off >>= 1) {
      ti += __shfl_down(ti, off, 64);
      tj += __shfl_down(tj, off, 64);
    }
    if (lane == 0) { ai[row * 2 + wave] = ti; aj[row * 2 + wave] = tj; }
    __syncthreads();
  }
}

// ---------------------------------------------------------------------------
// CSR build by DESTINATION (col): histogram -> exclusive scan -> fill.
// ---------------------------------------------------------------------------
__global__ __launch_bounds__(256) void k_deg(
    const int* __restrict__ ei, int* __restrict__ deg, int Ee) {
  int e = blockIdx.x * blockDim.x + threadIdx.x;
  if (e < Ee) atomicAdd(&deg[ei[Ee + e]], 1);
}

// block-level inclusive scan (Hillis-Steele) -> exclusive offsets + block sums
__global__ __launch_bounds__(256) void k_scan1(
    const int* __restrict__ deg, int* __restrict__ off, int* __restrict__ bsum, int Nn) {
  __shared__ int s[256];
  int t = threadIdx.x;
  int i = blockIdx.x * 256 + t;
  int v = (i < Nn) ? deg[i] : 0;
  s[t] = v;
  __syncthreads();
#pragma unroll
  for (int o = 1; o < 256; o <<= 1) {
    int xv = (t >= o) ? s[t - o] : 0;
    __syncthreads();
    s[t] += xv;
    __syncthreads();
  }
  if (i < Nn) off[i] = s[t] - v;          // exclusive
  if (t == 255) bsum[blockIdx.x] = s[t];  // block total
}

__global__ __launch_bounds__(256) void k_scan2(
    int* __restrict__ bsum, int* __restrict__ bpre, int nb) {
  __shared__ int s[256];
  int t = threadIdx.x;
  int v = (t < nb) ? bsum[t] : 0;
  s[t] = v;
  __syncthreads();
#pragma unroll
  for (int o = 1; o < 256; o <<= 1) {
    int xv = (t >= o) ? s[t - o] : 0;
    __syncthreads();
    s[t] += xv;
    __syncthreads();
  }
  if (t < nb) bpre[t] = s[t] - v;  // exclusive block prefix
}

__global__ __launch_bounds__(256) void k_scan3(
    int* __restrict__ off, const int* __restrict__ bpre, int Nn, int Ee) {
  int i = blockIdx.x * 256 + threadIdx.x;
  if (i < Nn) off[i] += bpre[blockIdx.x];
  if (i == 0) off[Nn] = Ee;
}

// ---------------------------------------------------------------------------
// K_fill: per-edge logits + leaky relu + exp; atomicAdd per-(src,head) sums;
// write CSR record {src, packed_attr, ea0, ea1} at off[dst] + cursor.
// Edge-emb logit term via 30-entry LDS table (dot(att_j, bond_emb[f][c])).
// ---------------------------------------------------------------------------
__global__ __launch_bounds__(256) void k_fill(
    const int* __restrict__ ei, const int* __restrict__ eattr,
    const float* __restrict__ att, const float* __restrict__ bemb,
    const float* __restrict__ ai, const float* __restrict__ aj,
    const int* __restrict__ off, int* __restrict__ wcur,
    float* __restrict__ sbuf, float4* __restrict__ rec, int Ee) {
  __shared__ float tbl[30];  // [f][c][hh] = f*10 + c*2 + hh
  int t = threadIdx.x;
  if (t < 30) {
    int f = t / 10, rem = t % 10, c = rem >> 1, hh = rem & 1;
    float sacc = 0.f;
    for (int d = 0; d < 64; ++d)
      sacc += att[hh * 128 + 64 + d] * bemb[(f * 5 + c) * 128 + hh * 64 + d];
    tbl[t] = sacc;
  }
  __syncthreads();
  int e = blockIdx.x * blockDim.x + t;
  if (e >= Ee) return;
  int r = ei[e], c = ei[Ee + e];
  int a0 = eattr[e * 3], a1 = eattr[e * 3 + 1], a2 = eattr[e * 3 + 2];
  float ea01[2];
#pragma unroll
  for (int hh = 0; hh < 2; ++hh) {
    float lg = ai[c * 2 + hh] + aj[r * 2 + hh] +
               tbl[a0 * 2 + hh] + tbl[10 + a1 * 2 + hh] + tbl[20 + a2 * 2 + hh];
    lg = lg >= 0.f ? lg : NEG_SLOPE * lg;
    float v = __expf(lg);
    ea01[hh] = v;
    atomicAdd(&sbuf[r * 2 + hh], v);
  }
  int pos = off[c] + atomicAdd(&wcur[c], 1);
  float4 rc;
  rc.x = __int_as_float(r);
  rc.y = __int_as_float(a0 | (a1 << 8) | (a2 << 16));
  rc.z = ea01[0];
  rc.w = ea01[1];
  rec[pos] = rc;
}

// ---------------------------------------------------------------------------
// K_gather: one wave per dst node, lane = d. Register accumulation over the
// node's CSR edge list — zero atomics. Fused head-mean + bias + output.
// ---------------------------------------------------------------------------
__global__ __launch_bounds__(256) void k_gather(
    const float4* __restrict__ rec, const int* __restrict__ off,
    const float* __restrict__ h, const float* __restrict__ sbuf,
    const float* __restrict__ bemb, const float* __restrict__ bias,
    float* __restrict__ out, int Nn) {
  __shared__ float bembs[3 * 5 * 128];
  for (int i = threadIdx.x; i < 3 * 5 * 128; i += blockDim.x)
    bembs[i] = bemb[i];
  __syncthreads();
  int wave = threadIdx.x >> 6;
  int lane = threadIdx.x & 63;
  int n = blockIdx.x * 4 + wave;
  if (n >= Nn) return;
  int p0 = off[n], p1 = off[n + 1];
  float acc0 = 0.f, acc1 = 0.f;
  for (int p = p0; p < p1; ++p) {
    float4 rc = rec[p];  // same addr across lanes -> broadcast
    int r = __float_as_int(rc.x);
    int pk = __float_as_int(rc.y);
    float al0 = rc.z / (sbuf[r * 2] + 1e-16f);
    float al1 = rc.w / (sbuf[r * 2 + 1] + 1e-16f);
    int a0 = (pk & 255) * 128;
    int a1 = ((pk >> 8) & 255) * 128 + 640;
    int a2 = ((pk >> 16) & 255) * 128 + 1280;
    float e0 = bembs[a0 + lane] + bembs[a1 + lane] + bembs[a2 + lane];
    float e1 = bembs[a0 + 64 + lane] + bembs[a1 + 64 + lane] + bembs[a2 + 64 + lane];
    acc0 += al0 * (h[(size_t)r * 128 + lane] + e0);
    acc1 += al1 * (h[(size_t)r * 128 + 64 + lane] + e1);
  }
  out[(size_t)n * 64 + lane] = 0.5f * (acc0 + acc1) + bias[lane];
}

extern "C" void kernel_launch(void* const* d_in, const int* in_sizes, int n_in,
                              void* d_out, int out_size, void* d_ws, size_t ws_size,
                              hipStream_t stream) {
  const float* x    = (const float*)d_in[0];
  const int*   ei   = (const int*)d_in[1];
  const int*   eatt = (const int*)d_in[2];
  const float* W    = (const float*)d_in[3];
  const float* bW   = (const float*)d_in[4];
  const float* att  = (const float*)d_in[5];
  const float* bias = (const float*)d_in[6];
  const float* bemb = (const float*)d_in[7];
  int Nn = in_sizes[0] / 64;
  int Ee = in_sizes[1] / 2;
  int nb1 = (Nn + 255) / 256;

  char* ws = (char*)d_ws;
  float* h = (float*)ws;     ws += (size_t)Nn * 128 * 4;
  float* ai = (float*)ws;    ws += (size_t)Nn * 2 * 4;
  float* aj = (float*)ws;    ws += (size_t)Nn * 2 * 4;
  float* sbuf = (float*)ws;  ws += (size_t)Nn * 2 * 4;
  int* deg = (int*)ws;       ws += (size_t)Nn * 4;
  int* wcur = (int*)ws;      ws += (size_t)Nn * 4;
  int* off = (int*)ws;       ws += (size_t)(Nn + 1) * 4;
  int* bsum = (int*)ws;      ws += (size_t)nb1 * 4;
  int* bpre = (int*)ws;      ws += (size_t)nb1 * 4;
  ws = (char*)(((uintptr_t)ws + 15) & ~(uintptr_t)15);
  float4* rec = (float4*)ws; ws += (size_t)Ee * 16;

  hipMemsetAsync(sbuf, 0, (size_t)Nn * 2 * 4, stream);
  hipMemsetAsync(deg, 0, (size_t)Nn * 4, stream);
  hipMemsetAsync(wcur, 0, (size_t)Nn * 4, stream);

  k1_gemm<<<1024, 128, 0, stream>>>(x, W, bW, att, h, ai, aj, Nn);
  k_deg<<<(Ee + 255) / 256, 256, 0, stream>>>(ei, deg, Ee);
  k_scan1<<<nb1, 256, 0, stream>>>(deg, off, bsum, Nn);
  k_scan2<<<1, 256, 0, stream>>>(bsum, bpre, nb1);
  k_scan3<<<nb1, 256, 0, stream>>>(off, bpre, Nn, Ee);
  k_fill<<<(Ee + 255) / 256, 256, 0, stream>>>(ei, eatt, att, bemb, ai, aj,
                                               off, wcur, sbuf, rec, Ee);
  k_gather<<<(Nn + 3) / 4, 256, 0, stream>>>(rec, off, h, sbuf, bemb, bias,
                                             (float*)d_out, Nn);
}